// Round 1
// baseline (162.512 us; speedup 1.0000x reference)
//
#include <hip/hip_runtime.h>
#include <math.h>

// D = 8192, BATCH = 4096
// out[b, j] = x[b] * w_col[j]
// w_col[j]  = s1[0] * s2[j] * FWHT(g_tilde)[j]
// g_tilde[i] = g_mu[i] + softplus(g_rho[i]) * epsilon[i]
//
// Derivation: W = s1[:,None] * H @ (g_tilde[:,None] * (H @ diag(s2))).
// w_col = first D elems of row-major flatten = W[0,:]. Row 0 of the Sylvester
// Hadamard is all +1 and H is symmetric, so W[0,j] = s1[0]*s2[j]*(H g_tilde)[j].
//
// Fully fused single launch: each block redundantly computes the 8192-pt FWHT
// in LDS (~1.4 us of LDS traffic — cheap), then streams 8 output rows with NT
// stores. 512 blocks x 1024 thr = 2 blocks/CU (32 KB LDS, 32 waves/CU).

#define WHVI_D 8192
#define WHVI_BATCH 4096
#define ROWS_PER_BLOCK 8   // 4096 / 512 blocks

typedef float v4f __attribute__((ext_vector_type(4)));

__global__ __launch_bounds__(1024) void whvi_fused(
    const float* __restrict__ x, const float* __restrict__ s1,
    const float* __restrict__ s2, const float* __restrict__ g_mu,
    const float* __restrict__ g_rho, const float* __restrict__ eps,
    float* __restrict__ out) {
  __shared__ float s[WHVI_D];
  const int tid = threadIdx.x;

  // g_tilde = g_mu + softplus(g_rho) * epsilon  (2 float4 per thread)
  {
    const float4* mu4 = (const float4*)g_mu;
    const float4* rh4 = (const float4*)g_rho;
    const float4* ep4 = (const float4*)eps;
    #pragma unroll
    for (int t = 0; t < 2; ++t) {
      int i = tid + t * 1024;
      float4 m = mu4[i], r = rh4[i], e = ep4[i];
      float4 g;
      g.x = m.x + (fmaxf(r.x, 0.0f) + log1pf(expf(-fabsf(r.x)))) * e.x;
      g.y = m.y + (fmaxf(r.y, 0.0f) + log1pf(expf(-fabsf(r.y)))) * e.y;
      g.z = m.z + (fmaxf(r.z, 0.0f) + log1pf(expf(-fabsf(r.z)))) * e.z;
      g.w = m.w + (fmaxf(r.w, 0.0f) + log1pf(expf(-fabsf(r.w)))) * e.w;
      ((float4*)s)[i] = g;
    }
  }

  // 13-stage in-place FWHT over LDS. Worst LDS aliasing is 2-way (free).
  for (int h = 1; h < WHVI_D; h <<= 1) {
    __syncthreads();
    #pragma unroll
    for (int t = 0; t < 4; ++t) {
      int p = tid + t * 1024;           // 4096 butterflies, 4 per thread
      int k = p & (h - 1);
      int i = ((p - k) << 1) + k;       // (p/h)*2h + k
      float a = s[i];
      float b = s[i + h];
      s[i]     = a + b;
      s[i + h] = a - b;
    }
  }
  __syncthreads();

  // Per-thread w fragments (2 float4 each): w = s1[0] * s2 * fwht(g_tilde)
  const float s10 = s1[0];
  const v4f* s24 = (const v4f*)s2;
  const v4f* sh4 = (const v4f*)s;
  v4f w0 = (s10 * s24[tid]) * sh4[tid];
  v4f w1 = (s10 * s24[tid + 1024]) * sh4[tid + 1024];

  // Stream 8 rows: out[row, :] = x[row] * w  (NT stores — pure streaming)
  const int row0 = blockIdx.x * ROWS_PER_BLOCK;
  #pragma unroll
  for (int r = 0; r < ROWS_PER_BLOCK; ++r) {
    const int row = row0 + r;
    const float xb = x[row];
    v4f* o4 = (v4f*)(out + (size_t)row * WHVI_D);
    __builtin_nontemporal_store(xb * w0, &o4[tid]);
    __builtin_nontemporal_store(xb * w1, &o4[tid + 1024]);
  }
}

extern "C" void kernel_launch(void* const* d_in, const int* in_sizes, int n_in,
                              void* d_out, int out_size, void* d_ws, size_t ws_size,
                              hipStream_t stream) {
  const float* x     = (const float*)d_in[0];  // (4096,1)
  const float* s1    = (const float*)d_in[1];  // (8192,)
  const float* s2    = (const float*)d_in[2];  // (8192,)
  const float* g_mu  = (const float*)d_in[3];  // (8192,)
  const float* g_rho = (const float*)d_in[4];  // (8192,)
  const float* eps   = (const float*)d_in[5];  // (8192,)
  float* out = (float*)d_out;                  // (4096, 8192)

  whvi_fused<<<WHVI_BATCH / ROWS_PER_BLOCK, 1024, 0, stream>>>(
      x, s1, s2, g_mu, g_rho, eps, out);
}

// Round 2
// 160.847 us; speedup vs baseline: 1.0104x; 1.0104x over previous
//
#include <hip/hip_runtime.h>
#include <math.h>

// D = 8192, BATCH = 4096
// out[b, j] = x[b] * w_col[j]
// w_col[j]  = s1[0] * s2[j] * FWHT(g_tilde)[j]
// g_tilde[i] = g_mu[i] + softplus(g_rho[i]) * epsilon[i]
//
// Two-kernel split (round 2):
//   A) whvi_make_w — ONE block computes the 8192-pt FWHT in LDS and writes
//      w (32 KB) to the workspace. Stages h=1,2 folded into registers
//      (float4-local), 11 LDS stages remain. ~4 us.
//   B) whvi_stream — pure streaming broadcast, structurally identical to the
//      6.27 TB/s fillBuffer: no LDS, no barriers, minimal VGPR. w fragment
//      lives in 8 registers/thread, 8 rows NT-stored per block.
// Rationale: round-1 profile showed the fused kernel < 85 us while resets hit
// 6.27 TB/s writes; the redundant per-block FWHT (13 barriers x 16 waves x 512
// blocks + 832 KB LDS traffic each) was serialized ahead of every store.

#define WHVI_D 8192
#define WHVI_BATCH 4096
#define ROWS_PER_BLOCK 8   // 4096 rows / 512 blocks

typedef float v4f __attribute__((ext_vector_type(4)));

// ---------------- Kernel A: compute w into workspace (1 block) -------------
__global__ __launch_bounds__(1024) void whvi_make_w(
    const float* __restrict__ s1, const float* __restrict__ s2,
    const float* __restrict__ g_mu, const float* __restrict__ g_rho,
    const float* __restrict__ eps, float* __restrict__ w) {
  __shared__ float s[WHVI_D];
  const int tid = threadIdx.x;

  // g_tilde = g_mu + softplus(g_rho)*eps, then FWHT stages h=1,2 in-register
  const float4* mu4 = (const float4*)g_mu;
  const float4* rh4 = (const float4*)g_rho;
  const float4* ep4 = (const float4*)eps;
  #pragma unroll
  for (int t = 0; t < 2; ++t) {
    int i = tid + t * 1024;
    float4 m = mu4[i], r = rh4[i], e = ep4[i];
    float g0 = m.x + (fmaxf(r.x, 0.0f) + log1pf(expf(-fabsf(r.x)))) * e.x;
    float g1 = m.y + (fmaxf(r.y, 0.0f) + log1pf(expf(-fabsf(r.y)))) * e.y;
    float g2 = m.z + (fmaxf(r.z, 0.0f) + log1pf(expf(-fabsf(r.z)))) * e.z;
    float g3 = m.w + (fmaxf(r.w, 0.0f) + log1pf(expf(-fabsf(r.w)))) * e.w;
    // stage h=1: pairs (0,1) (2,3)
    float b0 = g0 + g1, b1 = g0 - g1, b2 = g2 + g3, b3 = g2 - g3;
    // stage h=2: pairs (0,2) (1,3)
    float4 o;
    o.x = b0 + b2; o.y = b1 + b3; o.z = b0 - b2; o.w = b1 - b3;
    ((float4*)s)[i] = o;
  }

  // Remaining 11 stages (h = 4 .. 4096) in LDS. Worst aliasing 2-way (free).
  for (int h = 4; h < WHVI_D; h <<= 1) {
    __syncthreads();
    #pragma unroll
    for (int t = 0; t < 4; ++t) {
      int p = tid + t * 1024;           // 4096 butterflies, 4 per thread
      int k = p & (h - 1);
      int i = ((p - k) << 1) + k;       // (p/h)*2h + k
      float a = s[i];
      float b = s[i + h];
      s[i]     = a + b;
      s[i + h] = a - b;
    }
  }
  __syncthreads();

  // w = s1[0] * s2 * fwht(g_tilde) — regular stores so kernel B hits L2.
  const float s10 = s1[0];
  const v4f* s24 = (const v4f*)s2;
  const v4f* sh4 = (const v4f*)s;
  ((v4f*)w)[tid]        = (s10 * s24[tid])        * sh4[tid];
  ((v4f*)w)[tid + 1024] = (s10 * s24[tid + 1024]) * sh4[tid + 1024];
}

// ---------------- Kernel B: pure streaming broadcast -----------------------
__global__ __launch_bounds__(1024) void whvi_stream(
    const float* __restrict__ x, const float* __restrict__ w,
    float* __restrict__ out) {
  const int tid = threadIdx.x;
  const v4f* w4 = (const v4f*)w;
  const v4f w0 = w4[tid];
  const v4f w1 = w4[tid + 1024];

  const int row0 = blockIdx.x * ROWS_PER_BLOCK;
  #pragma unroll
  for (int r = 0; r < ROWS_PER_BLOCK; ++r) {
    const int row = row0 + r;
    const float xb = x[row];
    v4f* o4 = (v4f*)(out + (size_t)row * WHVI_D);
    __builtin_nontemporal_store(xb * w0, &o4[tid]);
    __builtin_nontemporal_store(xb * w1, &o4[tid + 1024]);
  }
}

extern "C" void kernel_launch(void* const* d_in, const int* in_sizes, int n_in,
                              void* d_out, int out_size, void* d_ws, size_t ws_size,
                              hipStream_t stream) {
  const float* x     = (const float*)d_in[0];  // (4096,1)
  const float* s1    = (const float*)d_in[1];  // (8192,)
  const float* s2    = (const float*)d_in[2];  // (8192,)
  const float* g_mu  = (const float*)d_in[3];  // (8192,)
  const float* g_rho = (const float*)d_in[4];  // (8192,)
  const float* eps   = (const float*)d_in[5];  // (8192,)
  float* out = (float*)d_out;                  // (4096, 8192)
  float* w   = (float*)d_ws;                   // 32 KB scratch for w_col

  whvi_make_w<<<1, 1024, 0, stream>>>(s1, s2, g_mu, g_rho, eps, w);
  whvi_stream<<<WHVI_BATCH / ROWS_PER_BLOCK, 1024, 0, stream>>>(x, w, out);
}

// Round 5
// 158.042 us; speedup vs baseline: 1.0283x; 1.0178x over previous
//
#include <hip/hip_runtime.h>
#include <math.h>

// D = 8192, BATCH = 4096
// out[b, j] = x[b] * w_col[j]
// w_col[j]  = s1[0] * s2[j] * FWHT(g_tilde)[j]
// g_tilde[i] = g_mu[i] + softplus(g_rho[i]) * epsilon[i]
//
// Round 4 (second resubmit after broker timeouts): round-2 profile proved the
// streaming epilogue runs at ~1.8 TB/s while the harness's fillBufferAligned
// (plain cached stores, 256-thr blocks) hits 6.27 TB/s on the same buffer.
// Kernel B is a structural clone of the fill: 256 threads/block, plain
// dwordx4 stores (no nontemporal — output is 128 MiB and fits in the 256 MiB
// L3, so cached stores can beat HBM), w fragment held in 8 regs/thread,
// 2 rows per block, perfectly contiguous per-instruction addresses.

#define WHVI_D 8192
#define WHVI_BATCH 4096

typedef float v4f __attribute__((ext_vector_type(4)));

// ---------------- Kernel A: compute w into workspace (1 block) -------------
__global__ __launch_bounds__(1024) void whvi_make_w(
    const float* __restrict__ s1, const float* __restrict__ s2,
    const float* __restrict__ g_mu, const float* __restrict__ g_rho,
    const float* __restrict__ eps, float* __restrict__ w) {
  __shared__ float s[WHVI_D];
  const int tid = threadIdx.x;

  // g_tilde = g_mu + softplus(g_rho)*eps, then FWHT stages h=1,2 in-register
  const float4* mu4 = (const float4*)g_mu;
  const float4* rh4 = (const float4*)g_rho;
  const float4* ep4 = (const float4*)eps;
  #pragma unroll
  for (int t = 0; t < 2; ++t) {
    int i = tid + t * 1024;
    float4 m = mu4[i], r = rh4[i], e = ep4[i];
    float g0 = m.x + (fmaxf(r.x, 0.0f) + log1pf(expf(-fabsf(r.x)))) * e.x;
    float g1 = m.y + (fmaxf(r.y, 0.0f) + log1pf(expf(-fabsf(r.y)))) * e.y;
    float g2 = m.z + (fmaxf(r.z, 0.0f) + log1pf(expf(-fabsf(r.z)))) * e.z;
    float g3 = m.w + (fmaxf(r.w, 0.0f) + log1pf(expf(-fabsf(r.w)))) * e.w;
    // stage h=1: pairs (0,1) (2,3)
    float b0 = g0 + g1, b1 = g0 - g1, b2 = g2 + g3, b3 = g2 - g3;
    // stage h=2: pairs (0,2) (1,3)
    float4 o;
    o.x = b0 + b2; o.y = b1 + b3; o.z = b0 - b2; o.w = b1 - b3;
    ((float4*)s)[i] = o;
  }

  // Remaining 11 stages (h = 4 .. 4096) in LDS. Worst aliasing 2-way (free).
  for (int h = 4; h < WHVI_D; h <<= 1) {
    __syncthreads();
    #pragma unroll
    for (int t = 0; t < 4; ++t) {
      int p = tid + t * 1024;           // 4096 butterflies, 4 per thread
      int k = p & (h - 1);
      int i = ((p - k) << 1) + k;       // (p/h)*2h + k
      float a = s[i];
      float b = s[i + h];
      s[i]     = a + b;
      s[i + h] = a - b;
    }
  }
  __syncthreads();

  // w = s1[0] * s2 * fwht(g_tilde) — plain stores so kernel B hits L2/L3.
  const float s10 = s1[0];
  const v4f* s24 = (const v4f*)s2;
  const v4f* sh4 = (const v4f*)s;
  ((v4f*)w)[tid]        = (s10 * s24[tid])        * sh4[tid];
  ((v4f*)w)[tid + 1024] = (s10 * s24[tid + 1024]) * sh4[tid + 1024];
}

// ---------------- Kernel B: fill-clone streaming broadcast -----------------
// 2048 blocks x 256 threads, 2 rows/block. Per row: thread t stores
// o4[t + k*256] (k=0..7) — each wave instruction covers 1 KB contiguous,
// 8 instructions cover the row's 32 KB. Plain cached stores.
#define STREAM_TPB 256
#define STREAM_ROWS 2
#define STREAM_BLOCKS (WHVI_BATCH / STREAM_ROWS)   // 2048

__global__ __launch_bounds__(STREAM_TPB) void whvi_stream(
    const float* __restrict__ x, const float* __restrict__ w,
    float* __restrict__ out) {
  const int t = threadIdx.x;
  const v4f* w4 = (const v4f*)w;

  v4f wf[8];
  #pragma unroll
  for (int k = 0; k < 8; ++k) wf[k] = w4[t + k * STREAM_TPB];

  const int row0 = blockIdx.x * STREAM_ROWS;
  #pragma unroll
  for (int r = 0; r < STREAM_ROWS; ++r) {
    const int row = row0 + r;
    const float xb = x[row];
    v4f* o4 = (v4f*)(out + (size_t)row * WHVI_D);
    #pragma unroll
    for (int k = 0; k < 8; ++k)
      o4[t + k * STREAM_TPB] = xb * wf[k];
  }
}

extern "C" void kernel_launch(void* const* d_in, const int* in_sizes, int n_in,
                              void* d_out, int out_size, void* d_ws, size_t ws_size,
                              hipStream_t stream) {
  const float* x     = (const float*)d_in[0];  // (4096,1)
  const float* s1    = (const float*)d_in[1];  // (8192,)
  const float* s2    = (const float*)d_in[2];  // (8192,)
  const float* g_mu  = (const float*)d_in[3];  // (8192,)
  const float* g_rho = (const float*)d_in[4];  // (8192,)
  const float* eps   = (const float*)d_in[5];  // (8192,)
  float* out = (float*)d_out;                  // (4096, 8192)
  float* w   = (float*)d_ws;                   // 32 KB scratch for w_col

  whvi_make_w<<<1, 1024, 0, stream>>>(s1, s2, g_mu, g_rho, eps, w);
  whvi_stream<<<STREAM_BLOCKS, STREAM_TPB, 0, stream>>>(x, w, out);
}